// Round 4
// baseline (410.162 us; speedup 1.0000x reference)
//
#include <hip/hip_runtime.h>

#define HH 32      // hidden size
#define NB 8       // batches per block
#define NT 256     // threads per block (4 waves)
#define TT 512     // max T staged in LDS

typedef float f32x4 __attribute__((ext_vector_type(4)));
typedef __bf16 bf16x8 __attribute__((ext_vector_type(8)));
typedef unsigned int u32;
typedef unsigned short u16;
typedef u32 u32x4 __attribute__((ext_vector_type(4)));

#if __has_builtin(__builtin_amdgcn_exp2f)
#define EXP2F(x) __builtin_amdgcn_exp2f(x)
#else
#define EXP2F(x) exp2f(x)
#endif
#if __has_builtin(__builtin_amdgcn_rcpf)
#define RCPF(x) __builtin_amdgcn_rcpf(x)
#else
#define RCPF(x) (1.0f / (x))
#endif

#define S_SIGM (-1.44269504f)   // -log2(e)
#define S_TANH (-2.88539008f)   // -2*log2(e)

// z is PRE-SCALED by S_SIGM / S_TANH (folded into weights+biases)
static __device__ __forceinline__ float sigm_pre(float zp) {
  return RCPF(1.0f + EXP2F(zp));
}
static __device__ __forceinline__ float tanh_pre(float zp) {
  return __builtin_fmaf(2.0f, RCPF(1.0f + EXP2F(zp)), -1.0f);
}
// A = weight fragment, B = state fragment
static __device__ __forceinline__ f32x4 mfma16(bf16x8 a, bf16x8 b, f32x4 c) {
  return __builtin_amdgcn_mfma_f32_16x16x32_bf16(a, b, c, 0, 0, 0);
}

// merge tile-B z into lanes with (lane&15)>=8: dest<l> = (l&15)<8 ? zA<l> : zB<l-8>
static __device__ __forceinline__ float merge_dpp(float zA, float zB) {
#if __has_builtin(__builtin_amdgcn_update_dpp)
  return __builtin_bit_cast(float, __builtin_amdgcn_update_dpp(
      __builtin_bit_cast(int, zA), __builtin_bit_cast(int, zB),
      0x118 /*row_shr:8*/, 0xF /*row_mask*/, 0xC /*bank_mask: lanes 8-15*/, false));
#else
  const int lane = threadIdx.x & 63;
  const float mv = __shfl_up(zB, 8, 16);
  return (lane & 8) ? mv : zA;
#endif
}

// round-to-nearest-even f32 -> bf16 bits in TOP 16, rest zeroed
static __device__ __forceinline__ u32 rne_hi(u32 b) {
  return (b + 0x7FFFu + ((b >> 16) & 1u)) & 0xFFFF0000u;
}
static __device__ __forceinline__ u32 pack_hi16(u32 a, u32 b) {
#if __has_builtin(__builtin_amdgcn_perm)
  return __builtin_amdgcn_perm(a, b, 0x03020706u);
#else
  return (b & 0xFFFF0000u) | (a >> 16);
#endif
}
static __device__ __forceinline__ void split8(const float f[8], bf16x8* hi, bf16x8* lo) {
  u32 r[8];
  float lof[8];
#pragma unroll
  for (int j = 0; j < 8; ++j) {
    u32 b = __builtin_bit_cast(u32, f[j]);
    r[j] = rne_hi(b);
    lof[j] = f[j] - __builtin_bit_cast(float, r[j]);  // exact
  }
  u32x4 hw, lw;
#pragma unroll
  for (int i = 0; i < 4; ++i) {
    hw[i] = pack_hi16(r[2 * i], r[2 * i + 1]);
    lw[i] = pack_hi16(__builtin_bit_cast(u32, lof[2 * i]),
                      __builtin_bit_cast(u32, lof[2 * i + 1]));
  }
  *hi = __builtin_bit_cast(bf16x8, hw);
  *lo = __builtin_bit_cast(bf16x8, lw);
}

// k-map (bank-conflict-free writes, used identically on A and B sides):
// fragment group kappa (=lane>>4), element e  <->  k = 8*kappa + 4*(e&1) + (e>>1)
// inverse for k=u: kappa = u>>3, e = 2*(u&3) + ((u>>2)&1)

// A-fragment of [4H][H] weight for tile `tile`, gate-permuted and PRE-SCALED:
// A row m -> gate row gi = (m&3)*H + 4*tile + (m>>2)   (m&3 = gate type)
static __device__ __forceinline__ void load_wfrag(const float* __restrict__ M,
                                                  int tile, int lane,
                                                  bf16x8* hi, bf16x8* lo) {
  const int m = lane & 15;
  const int q = m & 3;
  const int gi = q * HH + 4 * tile + (m >> 2);
  const int kappa = lane >> 4;
  const float s = (q == 2) ? S_TANH : S_SIGM;
  float f[8];
#pragma unroll
  for (int e = 0; e < 8; ++e)
    f[e] = M[gi * HH + 8 * kappa + 4 * (e & 1) + (e >> 1)] * s;
  split8(f, hi, lo);
}

static __device__ __forceinline__ void store_h(u16* hiA, u16* loA, int fw, float h) {
  const u32 b = __builtin_bit_cast(u32, h);
  const u32 r = rne_hi(b);
  hiA[fw] = (u16)(r >> 16);
  const float lof = h - __builtin_bit_cast(float, r);
  loA[fw] = (u16)(__builtin_bit_cast(u32, lof) >> 16);
}

__global__ void __launch_bounds__(NT)
lstm_fused_v4(const float* __restrict__ x,
              const float* __restrict__ W1, const float* __restrict__ b1,
              const float* __restrict__ Wih0, const float* __restrict__ Whh0,
              const float* __restrict__ bih0, const float* __restrict__ bhh0,
              const float* __restrict__ Wih1, const float* __restrict__ Whh1,
              const float* __restrict__ bih1, const float* __restrict__ bhh1,
              const float* __restrict__ W2, const float* __restrict__ b2,
              float* __restrict__ out, int T)
{
  // state B-fragments (bf16 hi/lo as u16), double-buffered; cols 8..15 stay 0
  __shared__ __align__(16) u16 h0hi[2][16 * HH], h0lo[2][16 * HH];
  __shared__ __align__(16) u16 h1hi[2][16 * HH], h1lo[2][16 * HH];
  __shared__ __align__(16) u16 hxhi[2][16 * HH], hxlo[2][16 * HH];
  __shared__ __align__(16) float xT[TT * NB];   // x transposed [t][b], 16 KB

  const int tid  = threadIdx.x;
  const int w    = tid >> 6;           // wave 0..3 -> tiles w and w+4
  const int lane = tid & 63;
  const int G    = lane >> 4;
  const int b0   = blockIdx.x * NB;

  // ---- weights as register-resident A-frags (2 tiles per wave) ----
  bf16x8 whh0hA, whh0lA, wih0hA, wih0lA, wih1hA, wih1lA, whh1hA, whh1lA;
  bf16x8 whh0hB, whh0lB, wih0hB, wih0lB, wih1hB, wih1lB, whh1hB, whh1lB;
  load_wfrag(Whh0, w,     lane, &whh0hA, &whh0lA);
  load_wfrag(Wih0, w,     lane, &wih0hA, &wih0lA);
  load_wfrag(Wih1, w,     lane, &wih1hA, &wih1lA);
  load_wfrag(Whh1, w,     lane, &whh1hA, &whh1lA);
  load_wfrag(Whh0, w + 4, lane, &whh0hB, &whh0lB);
  load_wfrag(Wih0, w + 4, lane, &wih0hB, &wih0lB);
  load_wfrag(Wih1, w + 4, lane, &wih1hB, &wih1lB);
  load_wfrag(Whh1, w + 4, lane, &whh1hB, &whh1lB);

  // pre-scaled biases folded into MFMA C-init (per-tile, keyed by G)
  f32x4 bias0A, bias0B, bias1A, bias1B;
  {
    const int uA = 4 * w + G, uB = 4 * (w + 4) + G;
#pragma unroll
    for (int q = 0; q < 4; ++q) {
      const float s = (q == 2) ? S_TANH : S_SIGM;
      bias0A[q] = (bih0[q * HH + uA] + bhh0[q * HH + uA]) * s;
      bias0B[q] = (bih0[q * HH + uB] + bhh0[q * HH + uB]) * s;
      bias1A[q] = (bih1[q * HH + uA] + bhh1[q * HH + uA]) * s;
      bias1B[q] = (bih1[q * HH + uB] + bhh1[q * HH + uB]) * s;
    }
  }
  const f32x4 fzero = {0.f, 0.f, 0.f, 0.f};

  // update role: lane owns (batch bq, unit uu); lanes (lane&15)>=8 take tile B
  const int bq = lane & 7;
  const int uu = 4 * w + G + 16 * ((lane >> 3) & 1);
  // frag u16 index for (bq, uu) under the k-map
  const int fw  = (bq + 16 * (uu >> 3)) * 8 + 2 * (uu & 3) + ((uu >> 2) & 1);
  const int frd = lane * 8;            // this lane's 16B frag read (u16 idx)

  const float W1u = W1[uu], b1u = b1[uu];
  const float W2a = W2[uu], W2b = W2[HH + uu];

  // ---- stage x transposed; zero-init frag buffers ----
  {
    const int row = tid >> 5;              // 0..7
    const int c0i = (tid & 31) * 16;       // 16 timesteps per thread
    if (c0i + 16 <= T) {
      const float* xp = x + (size_t)(b0 + row) * T + c0i;
#pragma unroll
      for (int j = 0; j < 16; j += 4) {
        float4 v = *(const float4*)(xp + j);
        xT[(c0i + j + 0) * NB + row] = v.x;
        xT[(c0i + j + 1) * NB + row] = v.y;
        xT[(c0i + j + 2) * NB + row] = v.z;
        xT[(c0i + j + 3) * NB + row] = v.w;
      }
    }
  }
  {  // zero all 6 frag arrays, both parities: 3072 u32 over 256 threads
    u32* z0 = (u32*)h0hi;   // arrays are contiguous enough? -- zero each explicitly
    (void)z0;
#pragma unroll
    for (int j = 0; j < 2; ++j) {
      ((u32*)h0hi[j])[tid] = 0; ((u32*)h0lo[j])[tid] = 0;
      ((u32*)h1hi[j])[tid] = 0; ((u32*)h1lo[j])[tid] = 0;
      ((u32*)hxhi[j])[tid] = 0; ((u32*)hxlo[j])[tid] = 0;
    }
  }
  __syncthreads();
  // hin(0) per owner lane (reads x directly from global)
  {
    const float hv = fmaxf(__builtin_fmaf(x[(size_t)(b0 + bq) * T], W1u, b1u), 0.0f);
    store_h(hxhi[0], hxlo[0], fw, hv);
  }
  float c0 = 0.0f, c1 = 0.0f, h0v = 0.0f, h1v = 0.0f;
  __syncthreads();

// One pipeline step: iter k does L0(t=k), L1(t=k-1), hin(k+1); ONE barrier.
#define STEP(kk, WB, DO_L0, DO_L1, DO_HIN)                                   \
  {                                                                          \
    const int RB = (WB) ^ 1;                                                 \
    const bf16x8 a0h = *(const bf16x8*)&h0hi[RB][frd];                       \
    const bf16x8 a0l = *(const bf16x8*)&h0lo[RB][frd];                       \
    bf16x8 a1h, a1l, axh, axl;                                               \
    if (DO_L1) { a1h = *(const bf16x8*)&h1hi[WB][frd];                       \
                 a1l = *(const bf16x8*)&h1lo[WB][frd]; }                     \
    if (DO_L0) { axh = *(const bf16x8*)&hxhi[WB][frd];                       \
                 axl = *(const bf16x8*)&hxlo[WB][frd]; }                     \
    if (DO_HIN) {  /* hin(kk+1) for own (bq,uu) into buf RB */               \
      const float xv = xT[((kk) + 1) * NB + bq];                             \
      const float hv = fmaxf(__builtin_fmaf(xv, W1u, b1u), 0.0f);            \
      store_h(hxhi[RB], hxlo[RB], fw, hv);                                   \
    }                                                                        \
    if (DO_L0) {                                                             \
      f32x4 rA = mfma16(whh0hA, a0h, bias0A);                                \
      rA = mfma16(whh0hA, a0l, rA);                                          \
      rA = mfma16(whh0lA, a0h, rA);                                          \
      f32x4 iA = mfma16(wih0hA, axh, fzero);                                 \
      iA = mfma16(wih0hA, axl, iA);                                          \
      iA = mfma16(wih0lA, axh, iA);                                          \
      f32x4 rB = mfma16(whh0hB, a0h, bias0B);                                \
      rB = mfma16(whh0hB, a0l, rB);                                          \
      rB = mfma16(whh0lB, a0h, rB);                                          \
      f32x4 iB = mfma16(wih0hB, axh, fzero);                                 \
      iB = mfma16(wih0hB, axl, iB);                                          \
      iB = mfma16(wih0lB, axh, iB);                                          \
      const f32x4 zA = rA + iA, zB = rB + iB;                                \
      f32x4 zm;                                                              \
      zm[0] = merge_dpp(zA[0], zB[0]); zm[1] = merge_dpp(zA[1], zB[1]);      \
      zm[2] = merge_dpp(zA[2], zB[2]); zm[3] = merge_dpp(zA[3], zB[3]);      \
      const float iv = sigm_pre(zm[0]), fv = sigm_pre(zm[1]);                \
      const float gv = tanh_pre(zm[2]), ov = sigm_pre(zm[3]);                \
      c0 = __builtin_fmaf(fv, c0, iv * gv);                                  \
      h0v = ov * tanh_pre(c0 * S_TANH);                                      \
      store_h(h0hi[WB], h0lo[WB], fw, h0v);                                  \
    }                                                                        \
    if (DO_L1) {                                                             \
      f32x4 rA = mfma16(whh1hA, a1h, bias1A);                                \
      rA = mfma16(whh1hA, a1l, rA);                                          \
      rA = mfma16(whh1lA, a1h, rA);                                          \
      f32x4 iA = mfma16(wih1hA, a0h, fzero);                                 \
      iA = mfma16(wih1hA, a0l, iA);                                          \
      iA = mfma16(wih1lA, a0h, iA);                                          \
      f32x4 rB = mfma16(whh1hB, a1h, bias1B);                                \
      rB = mfma16(whh1hB, a1l, rB);                                          \
      rB = mfma16(whh1lB, a1h, rB);                                          \
      f32x4 iB = mfma16(wih1hB, a0h, fzero);                                 \
      iB = mfma16(wih1hB, a0l, iB);                                          \
      iB = mfma16(wih1lB, a0h, iB);                                          \
      const f32x4 zA = rA + iA, zB = rB + iB;                                \
      f32x4 zm;                                                              \
      zm[0] = merge_dpp(zA[0], zB[0]); zm[1] = merge_dpp(zA[1], zB[1]);      \
      zm[2] = merge_dpp(zA[2], zB[2]); zm[3] = merge_dpp(zA[3], zB[3]);      \
      const float iv = sigm_pre(zm[0]), fv = sigm_pre(zm[1]);                \
      const float gv = tanh_pre(zm[2]), ov = sigm_pre(zm[3]);                \
      c1 = __builtin_fmaf(fv, c1, iv * gv);                                  \
      h1v = ov * tanh_pre(c1 * S_TANH);                                      \
      store_h(h1hi[RB], h1lo[RB], fw, h1v);                                  \
    }                                                                        \
    __syncthreads();                                                         \
  }

  STEP(0, 0, true, false, true);                  // k=0: L0 only
  for (int kk = 1; kk + 1 < T; kk += 2) {         // k = 1..T-2 in parity pairs
    STEP(kk, 1, true, true, true);
    STEP(kk + 1, 0, true, true, true);
  }
  STEP(T - 1, 1, true, true, false);              // k=T-1 (odd): no hin(T)
  STEP(T, 0, false, true, false);                 // k=T: L1 only

#undef STEP

  // ---- epilogue: out[b] = sum_u h0f[b,u]*W2[u] + h1f[b,u]*W2[H+u] + b2 ----
  xT[uu * NB + bq] = __builtin_fmaf(h0v, W2a, h1v * W2b);
  __syncthreads();
  if (tid < NB) {
    float acc = b2[0];
#pragma unroll
    for (int u = 0; u < HH; ++u) acc += xT[u * NB + tid];
    out[b0 + tid] = acc;
  }
}

extern "C" void kernel_launch(void* const* d_in, const int* in_sizes, int n_in,
                              void* d_out, int out_size, void* d_ws, size_t ws_size,
                              hipStream_t stream) {
  const float* x    = (const float*)d_in[0];
  const float* W1   = (const float*)d_in[1];
  const float* b1   = (const float*)d_in[2];
  const float* Wih0 = (const float*)d_in[3];
  const float* Whh0 = (const float*)d_in[4];
  const float* bih0 = (const float*)d_in[5];
  const float* bhh0 = (const float*)d_in[6];
  const float* Wih1 = (const float*)d_in[7];
  const float* Whh1 = (const float*)d_in[8];
  const float* bih1 = (const float*)d_in[9];
  const float* bhh1 = (const float*)d_in[10];
  const float* W2   = (const float*)d_in[11];
  const float* b2   = (const float*)d_in[12];

  const int B = out_size;                 // 4096
  const int I = in_sizes[1] / HH;         // 1
  const int T = in_sizes[0] / (B * I);    // 512
  const int blocks = B / NB;              // 512  -> 2 blocks/CU

  lstm_fused_v4<<<blocks, NT, 0, stream>>>(
      x, W1, b1, Wih0, Whh0, bih0, bhh0, Wih1, Whh1, bih1, bhh1, W2, b2,
      (float*)d_out, T);
}

// Round 5
// 233.426 us; speedup vs baseline: 1.7571x; 1.7571x over previous
//
#include <hip/hip_runtime.h>

#define HH 32      // hidden size
#define NB 16      // batches per block (full MFMA N-tile)
#define NT 1024    // threads per block (16 waves: 8 L0 + 8 L1)
#define TT 512     // max T staged in LDS

typedef float f32x4 __attribute__((ext_vector_type(4)));
typedef __bf16 bf16x8 __attribute__((ext_vector_type(8)));
typedef unsigned int u32;
typedef unsigned short u16;
typedef u32 u32x4 __attribute__((ext_vector_type(4)));

#if __has_builtin(__builtin_amdgcn_exp2f)
#define EXP2F(x) __builtin_amdgcn_exp2f(x)
#else
#define EXP2F(x) exp2f(x)
#endif
#if __has_builtin(__builtin_amdgcn_rcpf)
#define RCPF(x) __builtin_amdgcn_rcpf(x)
#else
#define RCPF(x) (1.0f / (x))
#endif

#define S_SIGM (-1.44269504f)   // -log2(e)
#define S_TANH (-2.88539008f)   // -2*log2(e)

// A = weight fragment, B = state fragment
static __device__ __forceinline__ f32x4 mfma16(bf16x8 a, bf16x8 b, f32x4 c) {
  return __builtin_amdgcn_mfma_f32_16x16x32_bf16(a, b, c, 0, 0, 0);
}

// round-to-nearest-even f32 -> bf16 bits in TOP 16, rest zeroed
static __device__ __forceinline__ u32 rne_hi(u32 b) {
  return (b + 0x7FFFu + ((b >> 16) & 1u)) & 0xFFFF0000u;
}
static __device__ __forceinline__ u32 pack_hi16(u32 a, u32 b) {
#if __has_builtin(__builtin_amdgcn_perm)
  return __builtin_amdgcn_perm(a, b, 0x03020706u);  // [b_hi16 : a_hi16]
#else
  return (b & 0xFFFF0000u) | (a >> 16);
#endif
}

// k-map (identical on A and B sides): group kappa=lane>>4, element e
//   <->  k = 8*kappa + 4*(e&1) + (e>>1)
// inverse for k=u: kappa=u>>3, e = 2*(u&3) + ((u>>2)&1)

// A-fragment (hi only, RNE) of [4H][H] weight for tile `tile`, gate-permuted
// and PRE-SCALED: A row m -> gate row gi = (m&3)*H + 4*tile + (m>>2)
static __device__ __forceinline__ bf16x8 load_wfrag_hi(const float* __restrict__ M,
                                                       int tile, int lane) {
  const int m = lane & 15;
  const int q = m & 3;
  const int gi = q * HH + 4 * tile + (m >> 2);
  const int kappa = lane >> 4;
  const float s = (q == 2) ? S_TANH : S_SIGM;
  u32 r[8];
#pragma unroll
  for (int e = 0; e < 8; ++e) {
    const float v = M[gi * HH + 8 * kappa + 4 * (e & 1) + (e >> 1)] * s;
    r[e] = rne_hi(__builtin_bit_cast(u32, v));
  }
  u32x4 hw;
#pragma unroll
  for (int i = 0; i < 4; ++i) hw[i] = pack_hi16(r[2 * i], r[2 * i + 1]);
  return __builtin_bit_cast(bf16x8, hw);
}

// store h as (hi, lo) bf16 pair at frag slot fw
static __device__ __forceinline__ void store_h(u16* hiA, u16* loA, int fw, float h) {
  const u32 b = __builtin_bit_cast(u32, h);
  const u32 r = rne_hi(b);
  hiA[fw] = (u16)(r >> 16);
  const float lof = h - __builtin_bit_cast(float, r);
  loA[fw] = (u16)(__builtin_bit_cast(u32, lof) >> 16);
}

__global__ void __launch_bounds__(NT)
lstm_fused_v5(const float* __restrict__ x,
              const float* __restrict__ W1, const float* __restrict__ b1,
              const float* __restrict__ Wih0, const float* __restrict__ Whh0,
              const float* __restrict__ bih0, const float* __restrict__ bhh0,
              const float* __restrict__ Wih1, const float* __restrict__ Whh1,
              const float* __restrict__ bih1, const float* __restrict__ bhh1,
              const float* __restrict__ W2, const float* __restrict__ b2,
              float* __restrict__ out, int T)
{
  // state B-fragments (bf16 hi/lo as u16), double-buffered; lane reads 16B at lane*16
  __shared__ __align__(16) u16 h0hi[2][NB * HH], h0lo[2][NB * HH];
  __shared__ __align__(16) u16 h1hi[2][NB * HH], h1lo[2][NB * HH];
  __shared__ __align__(16) u16 hxhi[2][NB * HH], hxlo[2][NB * HH];
  __shared__ __align__(16) float xT[TT * NB];   // x transposed [t][b], 32 KB

  const int tid  = threadIdx.x;
  const int lane = tid & 63;
  const int wS   = __builtin_amdgcn_readfirstlane(tid >> 6);  // wave id (SGPR)
  const bool isL0 = (wS < 8);
  const int tau  = wS & 7;             // gate tile of this wave's layer
  const int G    = lane >> 4;
  const int b0   = blockIdx.x * NB;

  // ---- role-selected weights (hi-only A-frags) and biases ----
  const float* Wr   = isL0 ? Whh0 : Whh1;
  const float* Wi_  = isL0 ? Wih0 : Wih1;
  const float* bihp = isL0 ? bih0 : bih1;
  const float* bhhp = isL0 ? bhh0 : bhh1;

  const bf16x8 wr = load_wfrag_hi(Wr,  tau, lane);
  const bf16x8 wi = load_wfrag_hi(Wi_, tau, lane);

  const int uu = 4 * tau + G;          // owned unit
  const int bq = lane & 15;            // owned batch (D col)
  f32x4 bias;
#pragma unroll
  for (int q = 0; q < 4; ++q) {
    const float s = (q == 2) ? S_TANH : S_SIGM;
    bias[q] = (bihp[q * HH + uu] + bhhp[q * HH + uu]) * s;
  }
  // frag u16 slot for (bq, uu) under the k-map
  const int fw  = (bq + 16 * (uu >> 3)) * 8 + 2 * (uu & 3) + ((uu >> 2) & 1);
  const int frd = lane * 8;            // this lane's 16B frag read (u16 idx)

  const float W1u = W1[uu], b1u = b1[uu];            // L0 role only
  const float W2v = W2[(isL0 ? 0 : HH) + uu];

  // ---- stage x transposed into LDS (4-way-conflict writes, one-time) ----
  {
    const int row = tid & 15;            // batch
    const int c0i = (tid >> 4) * 8;      // 8 timesteps per thread (0..504)
    if (c0i + 8 <= T) {
      const float* xp = x + (size_t)(b0 + row) * T + c0i;
      const float4 v0 = *(const float4*)(xp);
      const float4 v1 = *(const float4*)(xp + 4);
      xT[(c0i + 0) * NB + row] = v0.x;
      xT[(c0i + 1) * NB + row] = v0.y;
      xT[(c0i + 2) * NB + row] = v0.z;
      xT[(c0i + 3) * NB + row] = v0.w;
      xT[(c0i + 4) * NB + row] = v1.x;
      xT[(c0i + 5) * NB + row] = v1.y;
      xT[(c0i + 6) * NB + row] = v1.z;
      xT[(c0i + 7) * NB + row] = v1.w;
    }
  }
  // zero-init all frag buffers (6 arrays x 2 parities = 512 u32 each pair)
  if (tid < 512) {
    ((u32*)h0hi)[tid] = 0; ((u32*)h0lo)[tid] = 0;
    ((u32*)h1hi)[tid] = 0; ((u32*)h1lo)[tid] = 0;
    ((u32*)hxhi)[tid] = 0; ((u32*)hxlo)[tid] = 0;
  }
  __syncthreads();
  // hin(0) by L0 owner lanes
  if (isL0) {
    const float hv = fmaxf(__builtin_fmaf(x[(size_t)(b0 + bq) * T], W1u, b1u), 0.0f);
    store_h(hxhi[0], hxlo[0], fw, hv);
  }
  float cS = 0.0f, hS = 0.0f;
  __syncthreads();

#define GATES(z)                                                        \
    { const float ei = EXP2F(z[0]), ef = EXP2F(z[1]);                   \
      const float eg = EXP2F(z[2]), eo = EXP2F(z[3]);                   \
      const float iv = RCPF(1.0f + ei), fv = RCPF(1.0f + ef);           \
      const float gv = __builtin_fmaf(2.0f, RCPF(1.0f + eg), -1.0f);    \
      const float ov = RCPF(1.0f + eo);                                 \
      cS = __builtin_fmaf(fv, cS, iv * gv);                             \
      const float th = __builtin_fmaf(2.0f,                             \
          RCPF(1.0f + EXP2F(cS * S_TANH)), -1.0f);                      \
      hS = ov * th; }

// iter k: L0 waves do L0(t=k) + hin(k+1); L1 waves do L1(t=k-1). ONE barrier.
#define STEP(kk, WB, DO_L0, DO_L1, DO_HIN)                              \
  {                                                                     \
    const int RB = (WB) ^ 1;                                            \
    if (isL0) {                                                         \
      if (DO_L0) {                                                      \
        const bf16x8 shi = *(const bf16x8*)&h0hi[RB][frd];              \
        const bf16x8 slo = *(const bf16x8*)&h0lo[RB][frd];              \
        const bf16x8 phi = *(const bf16x8*)&hxhi[WB][frd];              \
        const bf16x8 plo = *(const bf16x8*)&hxlo[WB][frd];              \
        f32x4 z = mfma16(wi, plo, bias);                                \
        z = mfma16(wi, phi, z);                                         \
        z = mfma16(wr, slo, z);                                         \
        z = mfma16(wr, shi, z);                                         \
        if (DO_HIN) {                                                   \
          const float xv = xT[((kk) + 1) * NB + bq];                    \
          const float hv = fmaxf(__builtin_fmaf(xv, W1u, b1u), 0.0f);   \
          store_h(hxhi[RB], hxlo[RB], fw, hv);                          \
        }                                                               \
        GATES(z);                                                       \
        store_h(h0hi[WB], h0lo[WB], fw, hS);                            \
      }                                                                 \
    } else {                                                            \
      if (DO_L1) {                                                      \
        const bf16x8 shi = *(const bf16x8*)&h1hi[WB][frd];              \
        const bf16x8 slo = *(const bf16x8*)&h1lo[WB][frd];              \
        const bf16x8 phi = *(const bf16x8*)&h0hi[RB][frd];              \
        const bf16x8 plo = *(const bf16x8*)&h0lo[RB][frd];              \
        f32x4 z = mfma16(wi, plo, bias);                                \
        z = mfma16(wi, phi, z);                                         \
        z = mfma16(wr, slo, z);                                         \
        z = mfma16(wr, shi, z);                                         \
        GATES(z);                                                       \
        store_h(h1hi[RB], h1lo[RB], fw, hS);                            \
      }                                                                 \
    }                                                                   \
    __syncthreads();                                                    \
  }

  STEP(0, 0, true, false, true);                  // k=0: L0 only
  for (int kk = 1; kk + 1 < T; kk += 2) {         // k = 1..T-2 in parity pairs
    STEP(kk, 1, true, true, true);
    STEP(kk + 1, 0, true, true, true);
  }
  STEP(T - 1, 1, true, true, false);              // k=T-1 (odd): no hin(T)
  STEP(T, 0, false, true, false);                 // k=T: L1 only

#undef STEP
#undef GATES

  // ---- epilogue: out[b] = sum_u h0f[b,u]*W2[u] + h1f[b,u]*W2[H+u] + b2 ----
  xT[((isL0 ? 0 : HH) + uu) * NB + bq] = hS * W2v;   // reuse xT as [64][16]
  __syncthreads();
  if (tid < NB) {
    float acc = b2[0];
#pragma unroll
    for (int j = 0; j < 2 * HH; ++j) acc += xT[j * NB + tid];
    out[b0 + tid] = acc;
  }
}

extern "C" void kernel_launch(void* const* d_in, const int* in_sizes, int n_in,
                              void* d_out, int out_size, void* d_ws, size_t ws_size,
                              hipStream_t stream) {
  const float* x    = (const float*)d_in[0];
  const float* W1   = (const float*)d_in[1];
  const float* b1   = (const float*)d_in[2];
  const float* Wih0 = (const float*)d_in[3];
  const float* Whh0 = (const float*)d_in[4];
  const float* bih0 = (const float*)d_in[5];
  const float* bhh0 = (const float*)d_in[6];
  const float* Wih1 = (const float*)d_in[7];
  const float* Whh1 = (const float*)d_in[8];
  const float* bih1 = (const float*)d_in[9];
  const float* bhh1 = (const float*)d_in[10];
  const float* W2   = (const float*)d_in[11];
  const float* b2   = (const float*)d_in[12];

  const int B = out_size;                 // 4096
  const int I = in_sizes[1] / HH;         // 1
  const int T = in_sizes[0] / (B * I);    // 512
  const int blocks = B / NB;              // 256

  lstm_fused_v5<<<blocks, NT, 0, stream>>>(
      x, W1, b1, Wih0, Whh0, bih0, bhh0, Wih1, Whh1, bih1, bhh1, W2, b2,
      (float*)d_out, T);
}

// Round 6
// 232.419 us; speedup vs baseline: 1.7648x; 1.0043x over previous
//
#include <hip/hip_runtime.h>

#define HH 32      // hidden size
#define NB 16      // batches per block (full MFMA N-tile)
#define NT 512     // 8 waves: 4 L0 + 4 L1, each owning tiles (w&3, (w&3)+4)
#define TT 512     // max T staged in LDS

typedef float f32x4 __attribute__((ext_vector_type(4)));
typedef __bf16 bf16x8 __attribute__((ext_vector_type(8)));
typedef unsigned int u32;
typedef unsigned short u16;
typedef u32 u32x4 __attribute__((ext_vector_type(4)));

#if __has_builtin(__builtin_amdgcn_exp2f)
#define EXP2F(x) __builtin_amdgcn_exp2f(x)
#else
#define EXP2F(x) exp2f(x)
#endif
#if __has_builtin(__builtin_amdgcn_rcpf)
#define RCPF(x) __builtin_amdgcn_rcpf(x)
#else
#define RCPF(x) (1.0f / (x))
#endif

#define S_SIGM (-1.44269504f)   // -log2(e)
#define S_TANH (-2.88539008f)   // -2*log2(e)

// A = weight fragment, B = state fragment
static __device__ __forceinline__ f32x4 mfma16(bf16x8 a, bf16x8 b, f32x4 c) {
  return __builtin_amdgcn_mfma_f32_16x16x32_bf16(a, b, c, 0, 0, 0);
}

// round-to-nearest-even f32 -> bf16 bits in TOP 16, rest zeroed
static __device__ __forceinline__ u32 rne_hi(u32 b) {
  return (b + 0x7FFFu + ((b >> 16) & 1u)) & 0xFFFF0000u;
}
static __device__ __forceinline__ u32 pack_hi16(u32 a, u32 b) {
  // result = [b[31:16] : a[31:16]]  (low u16 = a's bf16)
#if __has_builtin(__builtin_amdgcn_perm)
  return __builtin_amdgcn_perm(a, b, 0x03020706u);
#else
  return (b & 0xFFFF0000u) | (a >> 16);
#endif
}
// packed (hi|lo) bf16 pair of f32 h: low u16 = RNE(h), high u16 = bf16(h - RNE(h))
static __device__ __forceinline__ u32 pack_hl(float h) {
  const u32 b = __builtin_bit_cast(u32, h);
  const u32 r = rne_hi(b);
  const float lo = h - __builtin_bit_cast(float, r);
  return pack_hi16(r, __builtin_bit_cast(u32, lo));
}

// Packed-K weight A-frag: K-slot s (=8*kappa+e) of half `half` carries unit
// j = 16*half + (s>>1); both slots 2j,2j+1 get the SAME bf16 weight (so one
// MFMA computes sum_j W[g,j]*(h_hi[j]+h_lo[j])). Rows m: gate q=m&3, unit
// offset m>>2 within tile; pre-scaled by -log2e / -2log2e.
static __device__ __forceinline__ bf16x8 load_wfrag_ph(const float* __restrict__ M,
                                                       int tile, int half, int lane) {
  const int m = lane & 15;
  const int q = m & 3;
  const int gi = q * HH + 4 * tile + (m >> 2);
  const int kappa = lane >> 4;
  const float s = (q == 2) ? S_TANH : S_SIGM;
  const float* p = M + gi * HH + 16 * half + 4 * kappa;
  u32x4 hw;
#pragma unroll
  for (int i = 0; i < 4; ++i) {
    const float v = p[i] * s;
    const u32 w16 = rne_hi(__builtin_bit_cast(u32, v)) >> 16;
    hw[i] = w16 | (w16 << 16);          // duplicated bf16 pair (slots 2j, 2j+1)
  }
  return __builtin_bit_cast(bf16x8, hw);
}

__global__ void __launch_bounds__(NT)
lstm_fused_v6(const float* __restrict__ x,
              const float* __restrict__ W1, const float* __restrict__ b1,
              const float* __restrict__ Wih0, const float* __restrict__ Whh0,
              const float* __restrict__ bih0, const float* __restrict__ bhh0,
              const float* __restrict__ Wih1, const float* __restrict__ Whh1,
              const float* __restrict__ bih1, const float* __restrict__ bhh1,
              const float* __restrict__ W2, const float* __restrict__ b2,
              float* __restrict__ out, int T)
{
  // packed state fragments: [parity][K-half][256 u32]; u32 slot for (b, u):
  //   half = u>>4, j = u&15, slot = (j>>2)*64 + b*4 + (j&3)
  __shared__ __align__(16) u32 h0P[2][2][256];
  __shared__ __align__(16) u32 h1P[2][2][256];
  __shared__ __align__(16) u32 hxP[2][2][256];
  __shared__ __align__(16) float xT[TT * NB];   // x transposed [t][b], 32 KB

  const int tid  = threadIdx.x;
  const int lane = tid & 63;
  const int wS   = __builtin_amdgcn_readfirstlane(tid >> 6);  // wave id
  const bool isL0 = (wS < 4);
  const int tq   = wS & 3;             // tile pair (tq, tq+4)
  const int kap  = lane >> 4;
  const int b    = lane & 15;
  const int b0   = blockIdx.x * NB;

  // ---- role-selected weights (packed-K A-frags, 2 tiles x 2 mats x 2 halves) ----
  const float* Wr   = isL0 ? Whh0 : Whh1;
  const float* Wi_  = isL0 ? Wih0 : Wih1;
  const float* bihp = isL0 ? bih0 : bih1;
  const float* bhhp = isL0 ? bhh0 : bhh1;

  const bf16x8 wrA0 = load_wfrag_ph(Wr,  tq,     0, lane);
  const bf16x8 wrA1 = load_wfrag_ph(Wr,  tq,     1, lane);
  const bf16x8 wiA0 = load_wfrag_ph(Wi_, tq,     0, lane);
  const bf16x8 wiA1 = load_wfrag_ph(Wi_, tq,     1, lane);
  const bf16x8 wrB0 = load_wfrag_ph(Wr,  tq + 4, 0, lane);
  const bf16x8 wrB1 = load_wfrag_ph(Wr,  tq + 4, 1, lane);
  const bf16x8 wiB0 = load_wfrag_ph(Wi_, tq + 4, 0, lane);
  const bf16x8 wiB1 = load_wfrag_ph(Wi_, tq + 4, 1, lane);

  const int uA = 4 * tq + kap;         // owned unit, tile A (in [0,16))
  const int uB = uA + 16;              // owned unit, tile B
  f32x4 biasA, biasB;
#pragma unroll
  for (int q = 0; q < 4; ++q) {
    const float s = (q == 2) ? S_TANH : S_SIGM;
    biasA[q] = (bihp[q * HH + uA] + bhhp[q * HH + uA]) * s;
    biasB[q] = (bihp[q * HH + uB] + bhhp[q * HH + uB]) * s;
  }
  // u32 store slot (same for half0/uA and half1/uB since uB&15 == uA)
  const int slot = tq * 64 + b * 4 + kap;
  const int frd  = lane * 8;           // u16 offset of this lane's 16B frag read

  const float W1a = W1[uA], b1a = b1[uA];
  const float W1b = W1[uB], b1b = b1[uB];
  const int   w2o = isL0 ? 0 : HH;
  const float W2a = W2[w2o + uA], W2b = W2[w2o + uB];

  // ---- stage x transposed into LDS (row = tid&15 -> ~4-way write conflicts) ----
  {
    const int row  = tid & 15;
    const int cbase = (tid >> 4) * 16;
    if (cbase + 16 <= T) {
      const float* xp = x + (size_t)(b0 + row) * T + cbase;
#pragma unroll
      for (int j = 0; j < 16; j += 4) {
        const float4 v = *(const float4*)(xp + j);
        xT[(cbase + j + 0) * NB + row] = v.x;
        xT[(cbase + j + 1) * NB + row] = v.y;
        xT[(cbase + j + 2) * NB + row] = v.z;
        xT[(cbase + j + 3) * NB + row] = v.w;
      }
    }
  }
  // zero-init packed state buffers: 3 arrays x 1024 u32
  ((u32*)h0P)[tid] = 0; ((u32*)h0P)[tid + 512] = 0;
  ((u32*)h1P)[tid] = 0; ((u32*)h1P)[tid + 512] = 0;
  ((u32*)hxP)[tid] = 0; ((u32*)hxP)[tid + 512] = 0;
  __syncthreads();

  // hin(0) into hxP[0]
  if (isL0) {
    const float xv = xT[b];
    hxP[0][0][slot] = pack_hl(fmaxf(__builtin_fmaf(xv, W1a, b1a), 0.0f));
    hxP[0][1][slot] = pack_hl(fmaxf(__builtin_fmaf(xv, W1b, b1b), 0.0f));
  }
  float cA = 0.0f, cB = 0.0f, hA = 0.0f, hB = 0.0f;
  __syncthreads();

#define GATES(z, c, h) {                                                \
    const float ei = EXP2F(z[0]), ef = EXP2F(z[1]);                     \
    const float eg = EXP2F(z[2]), eo = EXP2F(z[3]);                     \
    const float iv = RCPF(1.0f + ei), fv = RCPF(1.0f + ef);             \
    const float gv = __builtin_fmaf(2.0f, RCPF(1.0f + eg), -1.0f);      \
    const float ov = RCPF(1.0f + eo);                                   \
    c = __builtin_fmaf(fv, c, iv * gv);                                 \
    h = ov * __builtin_fmaf(2.0f, RCPF(1.0f + EXP2F(c * S_TANH)), -1.0f); \
  }

// iter k: L0 waves do L0(t=k) + hin(k+1); L1 waves do L1(t=k-1). ONE barrier.
#define STEP(kk, WB, DO_L0, DO_L1, DO_HIN)                              \
  {                                                                     \
    const int RB = (WB) ^ 1;                                            \
    if (isL0) {                                                         \
      if (DO_L0) {                                                      \
        const bf16x8 S0 = *(const bf16x8*)((const u16*)h0P[RB][0] + frd); \
        const bf16x8 S1 = *(const bf16x8*)((const u16*)h0P[RB][1] + frd); \
        const bf16x8 P0 = *(const bf16x8*)((const u16*)hxP[WB][0] + frd); \
        const bf16x8 P1 = *(const bf16x8*)((const u16*)hxP[WB][1] + frd); \
        f32x4 zA = mfma16(wiA1, P1, biasA);                             \
        f32x4 zB = mfma16(wiB1, P1, biasB);                             \
        zA = mfma16(wiA0, P0, zA);  zB = mfma16(wiB0, P0, zB);          \
        zA = mfma16(wrA1, S1, zA);  zB = mfma16(wrB1, S1, zB);          \
        zA = mfma16(wrA0, S0, zA);  zB = mfma16(wrB0, S0, zB);          \
        if (DO_HIN) {                                                   \
          const float xv = xT[((kk) + 1) * NB + b];                     \
          hxP[RB][0][slot] =                                            \
              pack_hl(fmaxf(__builtin_fmaf(xv, W1a, b1a), 0.0f));       \
          hxP[RB][1][slot] =                                            \
              pack_hl(fmaxf(__builtin_fmaf(xv, W1b, b1b), 0.0f));       \
        }                                                               \
        GATES(zA, cA, hA);                                              \
        GATES(zB, cB, hB);                                              \
        h0P[WB][0][slot] = pack_hl(hA);                                 \
        h0P[WB][1][slot] = pack_hl(hB);                                 \
      }                                                                 \
    } else {                                                            \
      if (DO_L1) {                                                      \
        const bf16x8 S0 = *(const bf16x8*)((const u16*)h1P[WB][0] + frd); \
        const bf16x8 S1 = *(const bf16x8*)((const u16*)h1P[WB][1] + frd); \
        const bf16x8 P0 = *(const bf16x8*)((const u16*)h0P[RB][0] + frd); \
        const bf16x8 P1 = *(const bf16x8*)((const u16*)h0P[RB][1] + frd); \
        f32x4 zA = mfma16(wiA1, P1, biasA);                             \
        f32x4 zB = mfma16(wiB1, P1, biasB);                             \
        zA = mfma16(wiA0, P0, zA);  zB = mfma16(wiB0, P0, zB);          \
        zA = mfma16(wrA1, S1, zA);  zB = mfma16(wrB1, S1, zB);          \
        zA = mfma16(wrA0, S0, zA);  zB = mfma16(wrB0, S0, zB);          \
        GATES(zA, cA, hA);                                              \
        GATES(zB, cB, hB);                                              \
        h1P[RB][0][slot] = pack_hl(hA);                                 \
        h1P[RB][1][slot] = pack_hl(hB);                                 \
      }                                                                 \
    }                                                                   \
    __syncthreads();                                                    \
  }

  STEP(0, 0, true, false, true);                  // k=0: L0 only
  for (int kk = 1; kk + 1 < T; kk += 2) {         // k = 1..T-2 in parity pairs
    STEP(kk, 1, true, true, true);
    STEP(kk + 1, 0, true, true, true);
  }
  STEP(T - 1, 1, true, true, false);              // k=T-1 (odd): no hin(T)
  STEP(T, 0, false, true, false);                 // k=T: L1 only

#undef STEP
#undef GATES

  // ---- epilogue: out[b] = sum_u h0f[b,u]*W2[u] + h1f[b,u]*W2[H+u] + b2 ----
  xT[(wS * 4 + kap) * NB + b] = __builtin_fmaf(hA, W2a, hB * W2b);
  __syncthreads();
  if (tid < NB) {
    float acc = b2[0];
#pragma unroll
    for (int j = 0; j < 32; ++j) acc += xT[j * NB + tid];
    out[b0 + tid] = acc;
  }
}

extern "C" void kernel_launch(void* const* d_in, const int* in_sizes, int n_in,
                              void* d_out, int out_size, void* d_ws, size_t ws_size,
                              hipStream_t stream) {
  const float* x    = (const float*)d_in[0];
  const float* W1   = (const float*)d_in[1];
  const float* b1   = (const float*)d_in[2];
  const float* Wih0 = (const float*)d_in[3];
  const float* Whh0 = (const float*)d_in[4];
  const float* bih0 = (const float*)d_in[5];
  const float* bhh0 = (const float*)d_in[6];
  const float* Wih1 = (const float*)d_in[7];
  const float* Whh1 = (const float*)d_in[8];
  const float* bih1 = (const float*)d_in[9];
  const float* bhh1 = (const float*)d_in[10];
  const float* W2   = (const float*)d_in[11];
  const float* b2   = (const float*)d_in[12];

  const int B = out_size;                 // 4096
  const int I = in_sizes[1] / HH;         // 1
  const int T = in_sizes[0] / (B * I);    // 512
  const int blocks = B / NB;              // 256 -> 1 block/CU

  lstm_fused_v6<<<blocks, NT, 0, stream>>>(
      x, W1, b1, Wih0, Whh0, bih0, bhh0, Wih1, Whh1, bih1, bhh1, W2, b2,
      (float*)d_out, T);
}

// Round 7
// 228.418 us; speedup vs baseline: 1.7957x; 1.0175x over previous
//
#include <hip/hip_runtime.h>

#define HH 32      // hidden size
#define NB 16      // batches per block (full MFMA N-tile)
#define NT 512     // 8 waves; wave w owns gate-tile w for BOTH layers
#define TT 512     // max T staged in LDS

typedef float f32x4 __attribute__((ext_vector_type(4)));
typedef __bf16 bf16x8 __attribute__((ext_vector_type(8)));
typedef unsigned int u32;
typedef unsigned short u16;
typedef u32 u32x4 __attribute__((ext_vector_type(4)));

#if __has_builtin(__builtin_amdgcn_exp2f)
#define EXP2F(x) __builtin_amdgcn_exp2f(x)
#else
#define EXP2F(x) exp2f(x)
#endif
#if __has_builtin(__builtin_amdgcn_rcpf)
#define RCPF(x) __builtin_amdgcn_rcpf(x)
#else
#define RCPF(x) (1.0f / (x))
#endif

#define S_SIGM (-1.44269504f)   // -log2(e)
#define S_TANH (-2.88539008f)   // -2*log2(e)

// A = weight fragment, B = state fragment
static __device__ __forceinline__ f32x4 mfma16(bf16x8 a, bf16x8 b, f32x4 c) {
  return __builtin_amdgcn_mfma_f32_16x16x32_bf16(a, b, c, 0, 0, 0);
}

// round-to-nearest-even f32 -> bf16 bits in TOP 16, rest zeroed
static __device__ __forceinline__ u32 rne_hi(u32 b) {
  return (b + 0x7FFFu + ((b >> 16) & 1u)) & 0xFFFF0000u;
}
static __device__ __forceinline__ u32 pack_hi16(u32 a, u32 b) {
  // result = [b[31:16] : a[31:16]]  (low u16 = a's bf16)
#if __has_builtin(__builtin_amdgcn_perm)
  return __builtin_amdgcn_perm(a, b, 0x03020706u);
#else
  return (b & 0xFFFF0000u) | (a >> 16);
#endif
}
// packed (hi|lo) bf16 pair of f32 h: low u16 = RNE(h), high u16 = bf16(h - RNE(h))
static __device__ __forceinline__ u32 pack_hl(float h) {
  const u32 b = __builtin_bit_cast(u32, h);
  const u32 r = rne_hi(b);
  const float lo = h - __builtin_bit_cast(float, r);
  return pack_hi16(r, __builtin_bit_cast(u32, lo));
}

// Packed-K weight A-frag: K-slot s (=8*kappa+e) of half `half` carries unit
// j = 16*half + (s>>1); both slots 2j,2j+1 get the SAME bf16 weight (so one
// MFMA computes sum_j W[g,j]*(h_hi[j]+h_lo[j])). Rows m: gate q=m&3, unit
// offset m>>2 within tile; pre-scaled by -log2e / -2log2e.
static __device__ __forceinline__ bf16x8 load_wfrag_ph(const float* __restrict__ M,
                                                       int tile, int half, int lane) {
  const int m = lane & 15;
  const int q = m & 3;
  const int gi = q * HH + 4 * tile + (m >> 2);
  const int kappa = lane >> 4;
  const float s = (q == 2) ? S_TANH : S_SIGM;
  const float* p = M + gi * HH + 16 * half + 4 * kappa;
  u32x4 hw;
#pragma unroll
  for (int i = 0; i < 4; ++i) {
    const float v = p[i] * s;
    const u32 w16 = rne_hi(__builtin_bit_cast(u32, v)) >> 16;
    hw[i] = w16 | (w16 << 16);          // duplicated bf16 pair (slots 2j, 2j+1)
  }
  return __builtin_bit_cast(bf16x8, hw);
}

__global__ void __launch_bounds__(NT)
lstm_fused_v7(const float* __restrict__ x,
              const float* __restrict__ W1, const float* __restrict__ b1,
              const float* __restrict__ Wih0, const float* __restrict__ Whh0,
              const float* __restrict__ bih0, const float* __restrict__ bhh0,
              const float* __restrict__ Wih1, const float* __restrict__ Whh1,
              const float* __restrict__ bih1, const float* __restrict__ bhh1,
              const float* __restrict__ W2, const float* __restrict__ b2,
              float* __restrict__ out, int T)
{
  // packed state fragments: [parity][K-half][256 u32]; u32 slot for (b, u):
  //   half = u>>4, slot = ((u&15)>>2)*64 + b*4 + (u&3)
  __shared__ __align__(16) u32 h0P[2][2][256];
  __shared__ __align__(16) u32 h1P[2][2][256];
  __shared__ __align__(16) u32 hxP[2][2][256];
  __shared__ __align__(16) float xT[TT * NB];   // x transposed [t][b], 32 KB

  const int tid  = threadIdx.x;
  const int lane = tid & 63;
  const int w    = tid >> 6;           // wave id == gate tile (0..7)
  const int G    = lane >> 4;
  const int b    = lane & 15;
  const int b0   = blockIdx.x * NB;

  // ---- weights: both layers, tile w, packed-K halves (8 bf16x8 total) ----
  const bf16x8 wr00 = load_wfrag_ph(Whh0, w, 0, lane);
  const bf16x8 wr01 = load_wfrag_ph(Whh0, w, 1, lane);
  const bf16x8 wi00 = load_wfrag_ph(Wih0, w, 0, lane);
  const bf16x8 wi01 = load_wfrag_ph(Wih0, w, 1, lane);
  const bf16x8 wr10 = load_wfrag_ph(Whh1, w, 0, lane);
  const bf16x8 wr11 = load_wfrag_ph(Whh1, w, 1, lane);
  const bf16x8 wi10 = load_wfrag_ph(Wih1, w, 0, lane);
  const bf16x8 wi11 = load_wfrag_ph(Wih1, w, 1, lane);

  const int uu = 4 * w + G;            // owned unit (0..31)
  f32x4 bias0, bias1;
#pragma unroll
  for (int q = 0; q < 4; ++q) {
    const float s = (q == 2) ? S_TANH : S_SIGM;
    bias0[q] = (bih0[q * HH + uu] + bhh0[q * HH + uu]) * s;
    bias1[q] = (bih1[q * HH + uu] + bhh1[q * HH + uu]) * s;
  }

  const int half = uu >> 4;                               // = w>>2
  const int slot = ((uu & 15) >> 2) * 64 + b * 4 + (uu & 3);  // (w&3)*64+4b+G
  const int frd  = lane * 8;           // u16 offset of this lane's 16B frag read

  const float W1u = W1[uu], b1u = b1[uu];
  const float W2a = W2[uu], W2b = W2[HH + uu];

  // ---- stage x transposed into LDS ----
  {
    const int row   = tid & 15;
    const int cbase = (tid >> 4) * 16;
    if (cbase + 16 <= T) {
      const float* xp = x + (size_t)(b0 + row) * T + cbase;
#pragma unroll
      for (int j = 0; j < 16; j += 4) {
        const float4 v = *(const float4*)(xp + j);
        xT[(cbase + j + 0) * NB + row] = v.x;
        xT[(cbase + j + 1) * NB + row] = v.y;
        xT[(cbase + j + 2) * NB + row] = v.z;
        xT[(cbase + j + 3) * NB + row] = v.w;
      }
    }
  }
  // zero-init packed state buffers: 3 arrays x 1024 u32
  ((u32*)h0P)[tid] = 0; ((u32*)h0P)[tid + 512] = 0;
  ((u32*)h1P)[tid] = 0; ((u32*)h1P)[tid + 512] = 0;
  ((u32*)hxP)[tid] = 0; ((u32*)hxP)[tid + 512] = 0;
  __syncthreads();

  // hin(0): one slot per lane
  {
    const float xv = xT[b];
    hxP[0][half][slot] = pack_hl(fmaxf(__builtin_fmaf(xv, W1u, b1u), 0.0f));
  }
  float c0 = 0.0f, c1 = 0.0f, h0v = 0.0f, h1v = 0.0f;
  __syncthreads();

#define GATES(z, c, h) {                                                \
    const float ei = EXP2F(z[0]), ef = EXP2F(z[1]);                     \
    const float eg = EXP2F(z[2]), eo = EXP2F(z[3]);                     \
    const float iv = RCPF(1.0f + ei), fv = RCPF(1.0f + ef);             \
    const float gv = __builtin_fmaf(2.0f, RCPF(1.0f + eg), -1.0f);      \
    const float ov = RCPF(1.0f + eo);                                   \
    c = __builtin_fmaf(fv, c, iv * gv);                                 \
    h = ov * __builtin_fmaf(2.0f, RCPF(1.0f + EXP2F(c * S_TANH)), -1.0f); \
  }

// iter k: every wave does L0(t=k) AND L1(t=k-1) (independent chains) + hin(k+1).
// ONE barrier. S-frags (h0[RB]) are shared by both chains.
#define STEP(kk, WB, DO_L0, DO_L1, DO_HIN)                               \
  {                                                                      \
    const int RB = (WB) ^ 1;                                             \
    const bf16x8 S0 = *(const bf16x8*)((const u16*)h0P[RB][0] + frd);    \
    const bf16x8 S1 = *(const bf16x8*)((const u16*)h0P[RB][1] + frd);    \
    if (DO_L0) {                                                         \
      const bf16x8 P0 = *(const bf16x8*)((const u16*)hxP[WB][0] + frd);  \
      const bf16x8 P1 = *(const bf16x8*)((const u16*)hxP[WB][1] + frd);  \
      f32x4 z0 = mfma16(wi01, P1, bias0);                                \
      z0 = mfma16(wi00, P0, z0);                                         \
      z0 = mfma16(wr01, S1, z0);                                         \
      z0 = mfma16(wr00, S0, z0);                                         \
      if (DO_HIN) {                                                      \
        const float xv = xT[((kk) + 1) * NB + b];                        \
        hxP[RB][half][slot] =                                            \
            pack_hl(fmaxf(__builtin_fmaf(xv, W1u, b1u), 0.0f));          \
      }                                                                  \
      GATES(z0, c0, h0v);                                                \
      h0P[WB][half][slot] = pack_hl(h0v);                                \
    }                                                                    \
    if (DO_L1) {                                                         \
      const bf16x8 T0 = *(const bf16x8*)((const u16*)h1P[WB][0] + frd);  \
      const bf16x8 T1 = *(const bf16x8*)((const u16*)h1P[WB][1] + frd);  \
      f32x4 z1 = mfma16(wi11, S1, bias1);                                \
      z1 = mfma16(wi10, S0, z1);                                         \
      z1 = mfma16(wr11, T1, z1);                                         \
      z1 = mfma16(wr10, T0, z1);                                         \
      GATES(z1, c1, h1v);                                                \
      h1P[RB][half][slot] = pack_hl(h1v);                                \
    }                                                                    \
    __syncthreads();                                                     \
  }

  STEP(0, 0, true, false, true);                  // k=0: L0 only + hin(1)
  for (int kk = 1; kk + 1 < T; kk += 2) {         // k = 1..T-2 in parity pairs
    STEP(kk, 1, true, true, true);
    STEP(kk + 1, 0, true, true, true);
  }
  STEP(T - 1, 1, true, true, false);              // k=T-1 (odd): no hin(T)
  STEP(T, 0, false, true, false);                 // k=T: L1 only

#undef STEP
#undef GATES

  // ---- epilogue: out[b] = sum_u h0f[b,u]*W2[u] + h1f[b,u]*W2[H+u] + b2 ----
  xT[uu * NB + b] = __builtin_fmaf(h0v, W2a, h1v * W2b);   // [32][16], unique slots
  __syncthreads();
  if (tid < NB) {
    float acc = b2[0];
#pragma unroll
    for (int u = 0; u < HH; ++u) acc += xT[u * NB + tid];
    out[b0 + tid] = acc;
  }
}

extern "C" void kernel_launch(void* const* d_in, const int* in_sizes, int n_in,
                              void* d_out, int out_size, void* d_ws, size_t ws_size,
                              hipStream_t stream) {
  const float* x    = (const float*)d_in[0];
  const float* W1   = (const float*)d_in[1];
  const float* b1   = (const float*)d_in[2];
  const float* Wih0 = (const float*)d_in[3];
  const float* Whh0 = (const float*)d_in[4];
  const float* bih0 = (const float*)d_in[5];
  const float* bhh0 = (const float*)d_in[6];
  const float* Wih1 = (const float*)d_in[7];
  const float* Whh1 = (const float*)d_in[8];
  const float* bih1 = (const float*)d_in[9];
  const float* bhh1 = (const float*)d_in[10];
  const float* W2   = (const float*)d_in[11];
  const float* b2   = (const float*)d_in[12];

  const int B = out_size;                 // 4096
  const int I = in_sizes[1] / HH;         // 1
  const int T = in_sizes[0] / (B * I);    // 512
  const int blocks = B / NB;              // 256 -> 1 block/CU

  lstm_fused_v7<<<blocks, NT, 0, stream>>>(
      x, W1, b1, Wih0, Whh0, bih0, bhh0, Wih1, Whh1, bih1, bhh1, W2, b2,
      (float*)d_out, T);
}